// Round 1
// baseline (133.826 us; speedup 1.0000x reference)
//
#include <hip/hip_runtime.h>
#include <math.h>

#define BX   1024
#define NA   16      // agents n
#define NM   16      // items m
#define MENU 256
#define KK   257     // MENU + 1 (null option)

__global__ __launch_bounds__(256) void auction_kernel(
    const float* __restrict__ bids,     // [B,16,16]
    const float* __restrict__ values,   // [B,16,16]
    const float* __restrict__ allocs,   // [B,256,16,16]
    const float* __restrict__ w,        // [B,16]
    const float* __restrict__ bvec,     // [B,256]
    const int*   __restrict__ tptr,     // scalar softmax_temp
    float* __restrict__ out)
{
    const int b   = blockIdx.x;
    const int tid = threadIdx.x;

    __shared__ __align__(16) float vb[256];   // value - bid, [n*16+m]
    __shared__ float wl[16];
    __shared__ float paw[KK][17];             // per_agent_welfare, padded stride
    __shared__ float tw_s[KK];
    __shared__ float bp_s[KK];
    __shared__ float ch_s[KK];
    __shared__ float red[8];

    // softmax_temp: harness may pass int32 or float32 bits; disambiguate.
    int iv = *tptr;
    float temp = (iv > 0 && iv < (1 << 24)) ? (float)iv : __int_as_float(iv);

    // ---- output layout (concatenated flat, return order) ----
    float* out_choice  = out;                                   // [B,257]
    float* out_item    = out + (size_t)BX * KK;                 // [B,256]
    float* out_util    = out_item + (size_t)BX * 256;           // [16,B]
    float* out_pay     = out_util + (size_t)NA * BX;            // [16,B]
    float* out_allocsp = out_pay  + (size_t)NA * BX;            // [B,257,256]
    float* out_bidrev  = out_allocsp + (size_t)BX * KK * 256;   // [16,B]

    // ---- preload per-b small data ----
    vb[tid]   = values[(size_t)b * 256 + tid] - bids[(size_t)b * 256 + tid];
    bp_s[tid] = bvec[(size_t)b * 256 + tid];
    if (tid < 16) { wl[tid] = w[b * 16 + tid]; paw[MENU][tid] = 0.0f; }
    if (tid == 0) { bp_s[MENU] = 0.0f; tw_s[MENU] = 0.0f; }
    __syncthreads();

    // ---- pass 1: stream allocs once -> paw[k][n], and copy to allocs_p ----
    {
        const float4* arow = (const float4*)(allocs + (size_t)b * MENU * 256);
        float4*       orow = (float4*)(out_allocsp + (size_t)b * KK * 256);
        const int ksub = tid >> 6;        // wave id: k = 4*kb + ksub
        const int l    = tid & 63;        // lane: covers elements 4l..4l+3
        const float4 vb4 = ((const float4*)vb)[l];
        const int n = l >> 2;             // agent index of this lane's 4 elems
        const float wn = wl[n];
        #pragma unroll 4
        for (int kb = 0; kb < 64; ++kb) {
            int k = kb * 4 + ksub;
            float4 a = arow[k * 64 + l];
            orow[k * 64 + l] = a;                       // allocs_p copy
            float d = a.x * vb4.x + a.y * vb4.y + a.z * vb4.z + a.w * vb4.w;
            d += __shfl_xor(d, 1);
            d += __shfl_xor(d, 2);                      // sum over 16 m's
            if ((l & 3) == 0) paw[k][n] = wn * d;
        }
        if (tid < 64) orow[MENU * 64 + tid] = make_float4(0.f, 0.f, 0.f, 0.f);
    }
    __syncthreads();

    // ---- main softmax over K=257 (thread t owns k=t; k=256 handled via 0) ----
    float tw = 0.0f;
    #pragma unroll
    for (int n = 0; n < 16; ++n) tw += paw[tid][n];
    tw_s[tid] = tw;
    const float logit = (tw + bp_s[tid]) * temp;

    const int wid = tid >> 6;
    float mx = logit;
    #pragma unroll
    for (int off = 32; off; off >>= 1) mx = fmaxf(mx, __shfl_xor(mx, off));
    if ((tid & 63) == 0) red[wid] = mx;
    __syncthreads();                                    // S1
    mx = fmaxf(fmaxf(red[0], red[1]), fmaxf(red[2], red[3]));
    mx = fmaxf(mx, 0.0f);                               // null-option logit = 0

    float e = __expf(logit - mx);
    float s = e;
    #pragma unroll
    for (int off = 32; off; off >>= 1) s += __shfl_xor(s, off);
    if ((tid & 63) == 0) red[4 + wid] = s;
    __syncthreads();                                    // S2 (also fences ch writes below? no - before)
    s = red[4] + red[5] + red[6] + red[7] + __expf(0.0f - mx);
    const float inv = 1.0f / s;

    const float c = e * inv;
    ch_s[tid] = c;
    out_choice[(size_t)b * KK + tid] = c;
    if (tid == 0) {
        float cn = __expf(0.0f - mx) * inv;
        ch_s[MENU] = cn;
        out_choice[(size_t)b * KK + MENU] = cn;
    }

    // chosen_sum + alloc_b = sum_k choice_k * (tw_k + b_k)   (null term = 0)
    float q = c * (tw + bp_s[tid]);
    #pragma unroll
    for (int off = 32; off; off >>= 1) q += __shfl_xor(q, off);
    __syncthreads();                                    // S3: red[0..3] reuse safe
    if ((tid & 63) == 0) red[wid] = q;
    __syncthreads();                                    // S4: also fences ch_s/tw_s
    const float cs_ab = red[0] + red[1] + red[2] + red[3];

    // ---- 16 counterfactual softmaxes: group ai (16 threads) per agent ----
    const int ai = tid >> 4;
    const int aj = tid & 15;
    float m1 = -1e30f;
    for (int k = aj; k < KK; k += 16) {
        float tr = tw_s[k] - paw[k][ai];
        m1 = fmaxf(m1, (tr + bp_s[k]) * temp);
    }
    #pragma unroll
    for (int off = 8; off; off >>= 1) m1 = fmaxf(m1, __shfl_xor(m1, off));
    float ss = 0.f, srs = 0.f, srb = 0.f;
    for (int k = aj; k < KK; k += 16) {
        float tr = tw_s[k] - paw[k][ai];
        float bp = bp_s[k];
        float eo = __expf((tr + bp) * temp - m1);
        ss  += eo;
        srs += eo * tr;
        srb += eo * bp;
    }
    #pragma unroll
    for (int off = 8; off; off >>= 1) {
        ss  += __shfl_xor(ss, off);
        srs += __shfl_xor(srs, off);
        srb += __shfl_xor(srb, off);
    }
    float paypre = 0.0f;
    if (aj == 0) paypre = (cs_ab - (srs + srb) / ss) / wl[ai];

    // ---- pass 2: sparse item_allocation (choice is ~one-hot) + epilogue ----
    float ia = 0.0f;
    const float* ab = allocs + (size_t)b * MENU * 256 + tid;
    for (int k = 0; k < MENU; ++k) {
        float cc = ch_s[k];                 // uniform across block
        if (cc > 1e-9f) ia += cc * ab[(size_t)k * 256];
    }
    out_item[(size_t)b * 256 + tid] = ia;

    float pb = ia * bids[(size_t)b * 256 + tid];
    float pv = ia * values[(size_t)b * 256 + tid];
    #pragma unroll
    for (int off = 1; off <= 8; off <<= 1) {
        pb += __shfl_xor(pb, off);          // sum over m within agent group
        pv += __shfl_xor(pv, off);
    }
    if (aj == 0) {
        float pay = paypre + pb;            // + bid_rev
        out_bidrev[(size_t)ai * BX + b] = pb;
        out_pay[(size_t)ai * BX + b]    = pay;
        out_util[(size_t)ai * BX + b]   = pv - pay;
    }
}

extern "C" void kernel_launch(void* const* d_in, const int* in_sizes, int n_in,
                              void* d_out, int out_size, void* d_ws, size_t ws_size,
                              hipStream_t stream) {
    (void)in_sizes; (void)n_in; (void)d_ws; (void)ws_size; (void)out_size;
    const float* bids   = (const float*)d_in[0];
    const float* values = (const float*)d_in[1];
    const float* allocs = (const float*)d_in[2];
    const float* w      = (const float*)d_in[3];
    const float* bvec   = (const float*)d_in[4];
    const int*   tptr   = (const int*)d_in[5];
    float* out = (float*)d_out;

    auction_kernel<<<BX, 256, 0, stream>>>(bids, values, allocs, w, bvec, tptr, out);
}